// Round 18
// baseline (210.974 us; speedup 1.0000x reference)
//
#include <hip/hip_runtime.h>
#include <hip/hip_bf16.h>

#define NPIX 9216
#define MTILES (NPIX / 16)    // 576

typedef __attribute__((ext_vector_type(4))) float f32x4;
typedef __attribute__((ext_vector_type(16))) float f32x16;
typedef __attribute__((ext_vector_type(8))) short bf16x8;
typedef __attribute__((ext_vector_type(2))) unsigned int u32x2;

__device__ __forceinline__ void gload_lds16(const void* g, void* l) {
  __builtin_amdgcn_global_load_lds(
      (const __attribute__((address_space(1))) unsigned int*)g,
      (__attribute__((address_space(3))) unsigned int*)l, 16, 0, 0);
}
__device__ __forceinline__ void gload_lds4(const void* g, void* l) {
  __builtin_amdgcn_global_load_lds(
      (const __attribute__((address_space(1))) unsigned int*)g,
      (__attribute__((address_space(3))) unsigned int*)l, 4, 0, 0);
}
#define LDS_OFF(p) ((unsigned)(unsigned long long)(const __attribute__((address_space(3))) char*)(const char*)(p))

// ---------------- Kernel 1: fused spectral + f,g,h projections ---------------
// (verbatim R15 + combine-counter zeroing; fgh completes before attn launches
// on the same stream, so counters are deterministically 0 each call)
__global__ __launch_bounds__(256) void fgh_kernel(
    const float* __restrict__ x,
    const float* __restrict__ Wf, const float* __restrict__ bfv,
    const float* __restrict__ Wg, const float* __restrict__ bgv,
    const float* __restrict__ Wh, const float* __restrict__ bhv,
    const float* __restrict__ uf, const float* __restrict__ ug,
    const float* __restrict__ uh,
    ushort* __restrict__ Qp, ushort* __restrict__ Kp, ushort* __restrict__ Vt2,
    unsigned* __restrict__ cnt) {
  __shared__ float vsh3[3][64];
  __shared__ float is_s[3];
  const int tid = threadIdx.x;
  if (blockIdx.y == 0 && tid < 4) cnt[blockIdx.x * 4 + tid] = 0;  // 144*4=576
  const int wv = tid >> 6, t = tid & 63;
  if (wv < 3) {
    const float* W = (wv == 0) ? Wf : (wv == 1) ? Wg : Wh;
    const float* u = (wv == 0) ? uf : (wv == 1) ? ug : uh;
    const int O = (wv == 2) ? 64 : 8;
    float v = 0.f;
    for (int o = 0; o < O; ++o) v += W[o * 64 + t] * u[o];
    float s = v * v;
    for (int off = 32; off; off >>= 1) s += __shfl_xor(s, off);
    vsh3[wv][t] = v / (sqrtf(s) + 1e-12f);
    float wvv = 0.f;
    if (t < O) { for (int c = 0; c < 64; ++c) wvv += W[t * 64 + c] * vsh3[wv][c]; }
    float s2 = (t < O) ? wvv * wvv : 0.f;
    for (int off = 32; off; off >>= 1) s2 += __shfl_xor(s2, off);
    const float nw = sqrtf(s2);
    if (t == 0) is_s[wv] = (nw + 1e-12f) / s2;
  }
  __syncthreads();

  const float LOG2E = 1.44269504f;
  const int px = tid & 63;
  const int rw = __builtin_amdgcn_readfirstlane(tid >> 6);
  const int r0 = blockIdx.y * 16 + rw * 4;
  const int p  = blockIdx.x * 64 + px;

  float xv[64];
  #pragma unroll
  for (int c = 0; c < 64; ++c) xv[c] = x[c * NPIX + p];

  const float* W0;
  float scl;
  if (r0 < 8)       { W0 = Wf + r0 * 64;        scl = is_s[0]; }
  else if (r0 < 16) { W0 = Wg + (r0 - 8) * 64;  scl = is_s[1]; }
  else              { W0 = Wh + (r0 - 16) * 64; scl = is_s[2]; }

  float acc[4] = {0.f, 0.f, 0.f, 0.f};
  #pragma unroll
  for (int c = 0; c < 64; ++c) {
    const float xc = xv[c];
    acc[0] += W0[c]       * xc;
    acc[1] += W0[64 + c]  * xc;
    acc[2] += W0[128 + c] * xc;
    acc[3] += W0[192 + c] * xc;
  }

  const int tile = p >> 5, nn = p & 31;
  const int kbase = tile * 512 + nn * 8;
  const int vfix = (nn >> 4) * 512 + ((nn >> 2) & 1) * 256
                 + (nn & 3) + 4 * ((nn >> 3) & 1);
  #pragma unroll
  for (int j = 0; j < 4; ++j) {
    const int r = r0 + j;
    if (r < 8) {
      const float val = (acc[j] * scl + bfv[r]) * LOG2E;
      const __hip_bfloat16 h = __float2bfloat16(val);
      Qp[p * 16 + r] = *(const ushort*)&h;
    } else if (r < 16) {
      const int rk = r - 8;
      const float val = acc[j] * scl + bgv[rk];
      const __hip_bfloat16 h = __float2bfloat16(val);
      Kp[kbase + rk] = *(const ushort*)&h;
    } else {
      const int rv = r - 16;
      const float val = acc[j] * scl + bhv[rv];
      const __hip_bfloat16 hv = __float2bfloat16(val);
      const int vidx = tile * 2048 + (rv >> 5) * 1024 + vfix + (rv & 31) * 8;
      Vt2[vidx] = *(const ushort*)&hv;
    }
  }
}

// -------- in-wave combine of one m-tile (pure sum; deterministic) ------------
__device__ __forceinline__ void wave_combine(
    int mt, int l, const ushort* __restrict__ Om, const float* __restrict__ Sm,
    const float* __restrict__ x, float gamma, float* __restrict__ out) {
  const float* Sb = Sm + (size_t)mt * 16 * 32;
  const ushort* Ob = Om + (size_t)mt * 16 * 1024;
  for (int e = l; e < 1024; e += 64) {
    const int m = e & 15, c = e >> 4;
    float L = 0.f, val = 0.f;
    #pragma unroll
    for (int s = 0; s < 16; ++s) {
      L += Sb[s * 32 + 16 + m];
      union { unsigned int i; float f; } cv;
      cv.i = ((unsigned int)Ob[s * 1024 + e]) << 16;
      val += cv.f;
    }
    const int idx = c * NPIX + mt * 16 + m;
    out[idx] = gamma * (val / L) + x[idx];
  }
}

// ---------------- Kernel 2: flash attention + fused combine ------------------
// Grid (72, 16), 256 threads (4 waves). attn body = R15 verbatim (verified).
// After writing its two mt-partials each wave does threadfence + atomicAdd on
// that mt's counter; the 16th arrival re-fences and combines the mt in-wave
// (rocPRIM-style threadfence reduction; result independent of arrival order).
__global__ __launch_bounds__(256) void attn_kernel(
    const ushort* __restrict__ Qp, const ushort* __restrict__ Kp,
    const ushort* __restrict__ Vt2,
    ushort* __restrict__ Om,   // [576 mt][16][1024] bf16 (e = c*16 + m)
    float* __restrict__ Sm,    // [576 mt][16][32]  f32 (ls at [16..31])
    unsigned* __restrict__ cnt,
    const float* __restrict__ x, const float* __restrict__ gammap,
    float* __restrict__ out) {
  constexpr int S = 16;
  constexpr int NSEG = NPIX / S;  // 576
  constexpr int NT = NSEG / 32;   // 18
  __shared__ ushort Vs[4][2048];  // 4 x 4KB
  __shared__ ushort Ks[4][512];   // 4 x 1KB
  const int tid  = threadIdx.x;
  const int w    = tid >> 6;
  const int l    = tid & 63;
  const int cc   = l & 31;
  const int h    = l >> 5;
  const int spl  = blockIdx.y;
  const int mrow = blockIdx.x * 128 + w * 32 + cc;

  bf16x8 qh = *(const bf16x8*)(Qp + mrow * 16);
  const bf16x8 zero8 = {0, 0, 0, 0, 0, 0, 0, 0};
  if (l >= 32) qh = zero8;        // kill pad-k contributions exactly
  asm volatile("" : "+v"(qh));

  const int n0 = spl * NSEG;
  const char* vsrc = (const char*)Vt2 + ((size_t)(n0 >> 5)) * 4096 + w * 1024 + l * 16;
  const char* ksrc = (const char*)Kp + ((size_t)(n0 >> 5)) * 1024 + w * 256 + l * 4;

  #define STAGE(t_) do {                                                  \
    const int b_ = (t_) & 3;                                              \
    gload_lds16(vsrc + (size_t)(t_) * 4096, (char*)&Vs[b_][0] + w * 1024);\
    gload_lds4 (ksrc + (size_t)(t_) * 1024, (char*)&Ks[b_][0] + w * 256); \
  } while (0)

  STAGE(0);
  STAGE(1);

  const unsigned ks_base = LDS_OFF(&Ks[0][0]);
  const unsigned vs_base = LDS_OFF(&Vs[0][0]);

  float ls = 0.f;
  const f32x16 zero16 = {0.f,0.f,0.f,0.f,0.f,0.f,0.f,0.f,
                         0.f,0.f,0.f,0.f,0.f,0.f,0.f,0.f};
  f32x16 accL = zero16, accH = zero16;   // c-halves 0..31 / 32..63

  for (int t = 0; t < NT; ++t) {
    const int b = t & 3;
    if (t + 2 < NT) {
      STAGE(t + 2);
      asm volatile("s_waitcnt vmcnt(4)" ::: "memory");
    } else if (t + 1 < NT) {
      asm volatile("s_waitcnt vmcnt(2)" ::: "memory");
    } else {
      asm volatile("s_waitcnt vmcnt(0)" ::: "memory");
    }
    __builtin_amdgcn_s_barrier();

    const unsigned kaddr = ks_base + b * 1024 + cc * 16;  // K row cc (bcast h)
    const unsigned vaddr = vs_base + b * 4096 + l * 16;   // linear per block
    bf16x8 kf, v00, v01, v10, v11;
    asm volatile("ds_read_b128 %0, %1"            : "=v"(kf)  : "v"(kaddr));
    asm volatile("ds_read_b128 %0, %1"            : "=v"(v00) : "v"(vaddr));
    asm volatile("ds_read_b128 %0, %1 offset:1024": "=v"(v01) : "v"(vaddr));
    asm volatile("ds_read_b128 %0, %1 offset:2048": "=v"(v10) : "v"(vaddr));
    asm volatile("ds_read_b128 %0, %1 offset:3072": "=v"(v11) : "v"(vaddr));
    asm volatile("s_waitcnt lgkmcnt(4)" ::: "memory");  // K ready (DS in-order)
    __builtin_amdgcn_sched_barrier(0);  // rule #18

    // ---- S^T[32n x 32m] = K . Q^T, single 32x32x16 MFMA (log2 domain) ----
    f32x16 s = zero16;
    s = __builtin_amdgcn_mfma_f32_32x32x16_bf16(kf, qh, s, 0, 0, 0);

    // ---- no-max softmax: P = exp2(S - 16); shift cancels in val/L ----
    float pj[16];
    #pragma unroll
    for (int r = 0; r < 16; ++r) pj[r] = exp2f(s[r] - 16.f);
    float lsum = 0.f;
    #pragma unroll
    for (int r = 0; r < 16; ++r) lsum += pj[r];
    ls += lsum;

    // ---- pack P into two A-frags (slot order == reg order) ----
    union { unsigned int u[4]; bf16x8 v; } pa0, pa1;
    #pragma unroll
    for (int jj = 0; jj < 4; ++jj) {
      unsigned int ra, rb;
      asm("v_cvt_pk_bf16_f32 %0, %1, %2" : "=v"(ra) : "v"(pj[2 * jj]), "v"(pj[2 * jj + 1]));
      asm("v_cvt_pk_bf16_f32 %0, %1, %2" : "=v"(rb) : "v"(pj[8 + 2 * jj]), "v"(pj[9 + 2 * jj]));
      pa0.u[jj] = ra;
      pa1.u[jj] = rb;
    }

    asm volatile("s_waitcnt lgkmcnt(0)" ::: "memory");  // V ready
    __builtin_amdgcn_sched_barrier(0);  // rule #18
    // ---- PV: O[32m x 64c], V frags mirror P's slot bijection ----
    accL = __builtin_amdgcn_mfma_f32_32x32x16_bf16(pa0.v, v00, accL, 0, 0, 0);
    accL = __builtin_amdgcn_mfma_f32_32x32x16_bf16(pa1.v, v01, accL, 0, 0, 0);
    accH = __builtin_amdgcn_mfma_f32_32x32x16_bf16(pa0.v, v10, accH, 0, 0, 0);
    accH = __builtin_amdgcn_mfma_f32_32x32x16_bf16(pa1.v, v11, accH, 0, 0, 0);
  }
  #undef STAGE

  // row-m sum: halves l and l+32 hold the two 16-n subsets of row m=l&31
  ls += __shfl_xor(ls, 32);

  const int mt0 = blockIdx.x * 8 + w * 2;
  ushort* Ob0 = Om + ((size_t)mt0 * S + spl) * 1024;
  ushort* Ob1 = Om + ((size_t)(mt0 + 1) * S + spl) * 1024;
  float*  Sb0 = Sm + ((size_t)mt0 * S + spl) * 32;
  float*  Sb1 = Sm + ((size_t)(mt0 + 1) * S + spl) * 32;
  // D layout: reg r -> m_local = (r&3) + 8*((r>>2)&1) + 4h + 16*(r>>3)
  #pragma unroll
  for (int ch = 0; ch < 2; ++ch) {
    const f32x16 a = (ch == 0) ? accL : accH;
    #pragma unroll
    for (int r = 0; r < 16; r += 2) {
      unsigned int pk;
      asm("v_cvt_pk_bf16_f32 %0, %1, %2" : "=v"(pk) : "v"(a[r]), "v"(a[r + 1]));
      const int m16 = (r & 3) + 8 * ((r >> 2) & 1) + 4 * h;  // even ✓
      ushort* Ob = (r < 8) ? Ob0 : Ob1;
      *(unsigned int*)(Ob + (ch * 32 + cc) * 16 + m16) = pk;
    }
  }
  if (l < 32) {
    float* SbX = (l < 16) ? Sb0 : Sb1;
    SbX[16 + (l & 15)] = ls;
  }

  // ---- fused combine: release partials, count arrivals, last wave combines --
  __threadfence();                       // release this wave's Om/Sm writes
  unsigned old0 = 0, old1 = 0;
  if (l == 0) {
    old0 = atomicAdd(&cnt[mt0], 1u);
    old1 = atomicAdd(&cnt[mt0 + 1], 1u);
  }
  old0 = __shfl(old0, 0);
  old1 = __shfl(old1, 0);
  const float gamma = gammap[0];
  if (old0 == S - 1) {                   // all 16 splits of mt0 done
    __threadfence();                     // acquire other blocks' partials
    wave_combine(mt0, l, Om, Sm, x, gamma, out);
  }
  if (old1 == S - 1) {
    __threadfence();
    wave_combine(mt0 + 1, l, Om, Sm, x, gamma, out);
  }
}

// ---------------- Kernel 3 (FALLBACK ONLY, small-ws path) --------------------
template <int S>
__global__ __launch_bounds__(256) void combine_kernel(
    const ushort* __restrict__ Om, const float* __restrict__ Sm,
    const float* __restrict__ x, const float* __restrict__ gammap,
    float* __restrict__ out) {
  const int mt = blockIdx.x >> 2;
  const int m0 = mt * 16;
  const int e  = (blockIdx.x & 3) * 256 + threadIdx.x;
  const float gamma = gammap[0];
  const float* Sb = Sm + (size_t)mt * S * 32;
  const ushort* Ob = Om + (size_t)mt * S * 1024;
  const int m = e & 15, c = e >> 4;
  float L = 0.f, val = 0.f;
  #pragma unroll
  for (int s = 0; s < S; ++s) {
    L += Sb[s * 32 + 16 + m];
    union { unsigned int i; float f; } cv;
    cv.i = ((unsigned int)Ob[s * 1024 + e]) << 16;
    val += cv.f;
  }
  const int idx = c * NPIX + m0 + m;
  out[idx] = gamma * (val / L) + x[idx];
}

// fallback attn without fused combine (S=8), structurally identical ----------
__global__ __launch_bounds__(256) void attn_kernel8(
    const ushort* __restrict__ Qp, const ushort* __restrict__ Kp,
    const ushort* __restrict__ Vt2,
    ushort* __restrict__ Om, float* __restrict__ Sm) {
  constexpr int S = 8;
  constexpr int NSEG = NPIX / S;
  constexpr int NT = NSEG / 32;
  __shared__ ushort Vs[4][2048];
  __shared__ ushort Ks[4][512];
  const int tid  = threadIdx.x;
  const int w    = tid >> 6;
  const int l    = tid & 63;
  const int cc   = l & 31;
  const int h    = l >> 5;
  const int spl  = blockIdx.y;
  const int mrow = blockIdx.x * 128 + w * 32 + cc;

  bf16x8 qh = *(const bf16x8*)(Qp + mrow * 16);
  const bf16x8 zero8 = {0, 0, 0, 0, 0, 0, 0, 0};
  if (l >= 32) qh = zero8;
  asm volatile("" : "+v"(qh));

  const int n0 = spl * NSEG;
  const char* vsrc = (const char*)Vt2 + ((size_t)(n0 >> 5)) * 4096 + w * 1024 + l * 16;
  const char* ksrc = (const char*)Kp + ((size_t)(n0 >> 5)) * 1024 + w * 256 + l * 4;

  #define STAGE(t_) do {                                                  \
    const int b_ = (t_) & 3;                                              \
    gload_lds16(vsrc + (size_t)(t_) * 4096, (char*)&Vs[b_][0] + w * 1024);\
    gload_lds4 (ksrc + (size_t)(t_) * 1024, (char*)&Ks[b_][0] + w * 256); \
  } while (0)
  STAGE(0);
  STAGE(1);
  const unsigned ks_base = LDS_OFF(&Ks[0][0]);
  const unsigned vs_base = LDS_OFF(&Vs[0][0]);
  float ls = 0.f;
  const f32x16 zero16 = {0.f,0.f,0.f,0.f,0.f,0.f,0.f,0.f,
                         0.f,0.f,0.f,0.f,0.f,0.f,0.f,0.f};
  f32x16 accL = zero16, accH = zero16;
  for (int t = 0; t < NT; ++t) {
    const int b = t & 3;
    if (t + 2 < NT) {
      STAGE(t + 2);
      asm volatile("s_waitcnt vmcnt(4)" ::: "memory");
    } else if (t + 1 < NT) {
      asm volatile("s_waitcnt vmcnt(2)" ::: "memory");
    } else {
      asm volatile("s_waitcnt vmcnt(0)" ::: "memory");
    }
    __builtin_amdgcn_s_barrier();
    const unsigned kaddr = ks_base + b * 1024 + cc * 16;
    const unsigned vaddr = vs_base + b * 4096 + l * 16;
    bf16x8 kf, v00, v01, v10, v11;
    asm volatile("ds_read_b128 %0, %1"            : "=v"(kf)  : "v"(kaddr));
    asm volatile("ds_read_b128 %0, %1"            : "=v"(v00) : "v"(vaddr));
    asm volatile("ds_read_b128 %0, %1 offset:1024": "=v"(v01) : "v"(vaddr));
    asm volatile("ds_read_b128 %0, %1 offset:2048": "=v"(v10) : "v"(vaddr));
    asm volatile("ds_read_b128 %0, %1 offset:3072": "=v"(v11) : "v"(vaddr));
    asm volatile("s_waitcnt lgkmcnt(4)" ::: "memory");
    __builtin_amdgcn_sched_barrier(0);
    f32x16 s = zero16;
    s = __builtin_amdgcn_mfma_f32_32x32x16_bf16(kf, qh, s, 0, 0, 0);
    float pj[16];
    #pragma unroll
    for (int r = 0; r < 16; ++r) pj[r] = exp2f(s[r] - 16.f);
    float lsum = 0.f;
    #pragma unroll
    for (int r = 0; r < 16; ++r) lsum += pj[r];
    ls += lsum;
    union { unsigned int u[4]; bf16x8 v; } pa0, pa1;
    #pragma unroll
    for (int jj = 0; jj < 4; ++jj) {
      unsigned int ra, rb;
      asm("v_cvt_pk_bf16_f32 %0, %1, %2" : "=v"(ra) : "v"(pj[2 * jj]), "v"(pj[2 * jj + 1]));
      asm("v_cvt_pk_bf16_f32 %0, %1, %2" : "=v"(rb) : "v"(pj[8 + 2 * jj]), "v"(pj[9 + 2 * jj]));
      pa0.u[jj] = ra;
      pa1.u[jj] = rb;
    }
    asm volatile("s_waitcnt lgkmcnt(0)" ::: "memory");
    __builtin_amdgcn_sched_barrier(0);
    accL = __builtin_amdgcn_mfma_f32_32x32x16_bf16(pa0.v, v00, accL, 0, 0, 0);
    accL = __builtin_amdgcn_mfma_f32_32x32x16_bf16(pa1.v, v01, accL, 0, 0, 0);
    accH = __builtin_amdgcn_mfma_f32_32x32x16_bf16(pa0.v, v10, accH, 0, 0, 0);
    accH = __builtin_amdgcn_mfma_f32_32x32x16_bf16(pa1.v, v11, accH, 0, 0, 0);
  }
  #undef STAGE
  ls += __shfl_xor(ls, 32);
  const size_t mt0 = (size_t)blockIdx.x * 8 + w * 2;
  ushort* Ob0 = Om + (mt0 * S + spl) * 1024;
  ushort* Ob1 = Om + ((mt0 + 1) * S + spl) * 1024;
  float*  Sb0 = Sm + (mt0 * S + spl) * 32;
  float*  Sb1 = Sm + ((mt0 + 1) * S + spl) * 32;
  #pragma unroll
  for (int ch = 0; ch < 2; ++ch) {
    const f32x16 a = (ch == 0) ? accL : accH;
    #pragma unroll
    for (int r = 0; r < 16; r += 2) {
      unsigned int pk;
      asm("v_cvt_pk_bf16_f32 %0, %1, %2" : "=v"(pk) : "v"(a[r]), "v"(a[r + 1]));
      const int m16 = (r & 3) + 8 * ((r >> 2) & 1) + 4 * h;
      ushort* Ob = (r < 8) ? Ob0 : Ob1;
      *(unsigned int*)(Ob + (ch * 32 + cc) * 16 + m16) = pk;
    }
  }
  if (l < 32) {
    float* SbX = (l < 16) ? Sb0 : Sb1;
    SbX[16 + (l & 15)] = ls;
  }
}

// ---------------- launcher ---------------------------------------------------
extern "C" void kernel_launch(void* const* d_in, const int* in_sizes, int n_in,
                              void* d_out, int out_size, void* d_ws, size_t ws_size,
                              hipStream_t stream) {
  const float* x     = (const float*)d_in[0];
  const float* Wf    = (const float*)d_in[1];
  const float* bf    = (const float*)d_in[2];
  const float* Wg    = (const float*)d_in[3];
  const float* bg    = (const float*)d_in[4];
  const float* Wh    = (const float*)d_in[5];
  const float* bh    = (const float*)d_in[6];
  const float* gamma = (const float*)d_in[7];
  const float* uf    = (const float*)d_in[8];
  const float* ug    = (const float*)d_in[9];
  const float* uh    = (const float*)d_in[10];
  float* out = (float*)d_out;

  char* ws = (char*)d_ws;
  ushort* Qp  = (ushort*)(ws + 256);                                 // 294912 B
  ushort* Kp  = (ushort*)(ws + 256 + NPIX * 16 * 2);                 // 294912 B
  ushort* Vt2 = (ushort*)(ws + 256 + 2 * NPIX * 16 * 2);             // 1179648 B
  const size_t off = 256 + (size_t)2 * NPIX * 16 * 2 + (size_t)NPIX * 64 * 2;
  ushort* Om = (ushort*)(ws + off);
  const size_t omSz16 = (size_t)MTILES * 16 * 1024 * 2;
  const size_t smSz16 = (size_t)MTILES * 16 * 32 * 4;
  const size_t need16 = off + omSz16 + smSz16 + MTILES * 4;

  if (ws_size >= need16) {
    float*    Sm  = (float*)(ws + off + omSz16);
    unsigned* cnt = (unsigned*)(ws + off + omSz16 + smSz16);
    fgh_kernel<<<dim3(NPIX / 64, 5), 256, 0, stream>>>(x, Wf, bf, Wg, bg, Wh, bh,
                                                       uf, ug, uh, Qp, Kp, Vt2, cnt);
    attn_kernel<<<dim3(NPIX / 128, 16), 256, 0, stream>>>(Qp, Kp, Vt2, Om, Sm,
                                                          cnt, x, gamma, out);
  } else {
    float*    Sm  = (float*)(ws + off + (size_t)MTILES * 8 * 1024 * 2);
    unsigned* cnt = (unsigned*)(ws + off + (size_t)MTILES * 8 * 1024 * 2 +
                                (size_t)MTILES * 8 * 32 * 4);
    fgh_kernel<<<dim3(NPIX / 64, 5), 256, 0, stream>>>(x, Wf, bf, Wg, bg, Wh, bh,
                                                       uf, ug, uh, Qp, Kp, Vt2, cnt);
    attn_kernel8<<<dim3(NPIX / 128, 8), 256, 0, stream>>>(Qp, Kp, Vt2, Om, Sm);
    combine_kernel<8><<<MTILES * 4, 256, 0, stream>>>(Om, Sm, x, gamma, out);
  }
}

// Round 19
// 71.915 us; speedup vs baseline: 2.9337x; 2.9337x over previous
//
#include <hip/hip_runtime.h>
#include <hip/hip_bf16.h>

#define NPIX 9216
#define MTILES (NPIX / 16)    // 576

typedef __attribute__((ext_vector_type(4))) float f32x4;
typedef __attribute__((ext_vector_type(16))) float f32x16;
typedef __attribute__((ext_vector_type(8))) short bf16x8;
typedef __attribute__((ext_vector_type(2))) unsigned int u32x2;

__device__ __forceinline__ void gload_lds16(const void* g, void* l) {
  __builtin_amdgcn_global_load_lds(
      (const __attribute__((address_space(1))) unsigned int*)g,
      (__attribute__((address_space(3))) unsigned int*)l, 16, 0, 0);
}
__device__ __forceinline__ void gload_lds4(const void* g, void* l) {
  __builtin_amdgcn_global_load_lds(
      (const __attribute__((address_space(1))) unsigned int*)g,
      (__attribute__((address_space(3))) unsigned int*)l, 4, 0, 0);
}
#define LDS_OFF(p) ((unsigned)(unsigned long long)(const __attribute__((address_space(3))) char*)(const char*)(p))

// ---------------- Kernel 1: fused spectral + f,g,h projections ---------------
// Waves 0/1/2 compute sigma_f/g/h in parallel, then all 4 waves do the GEMV.
// Grid (144, 5): block = 64 pixels x 16 rows.
// Layouts for the 32x32-MFMA attention:
//   Qp [NPIX][16] bf16 — q * log2e at [0..7].
//   Kp [288 tiles][1KB] — row nn at byte nn*16 (k 0..7); bytes 512.. unused.
//   Vt2 [288 tiles][4KB] — PV B-frag order (mirrors P slot order).
__global__ __launch_bounds__(256) void fgh_kernel(
    const float* __restrict__ x,
    const float* __restrict__ Wf, const float* __restrict__ bfv,
    const float* __restrict__ Wg, const float* __restrict__ bgv,
    const float* __restrict__ Wh, const float* __restrict__ bhv,
    const float* __restrict__ uf, const float* __restrict__ ug,
    const float* __restrict__ uh,
    ushort* __restrict__ Qp, ushort* __restrict__ Kp, ushort* __restrict__ Vt2) {
  __shared__ float vsh3[3][64];
  __shared__ float is_s[3];
  const int tid = threadIdx.x;
  const int wv = tid >> 6, t = tid & 63;
  if (wv < 3) {  // 3 independent sigma chains, one per wave
    const float* W = (wv == 0) ? Wf : (wv == 1) ? Wg : Wh;
    const float* u = (wv == 0) ? uf : (wv == 1) ? ug : uh;
    const int O = (wv == 2) ? 64 : 8;
    float v = 0.f;
    for (int o = 0; o < O; ++o) v += W[o * 64 + t] * u[o];
    float s = v * v;
    for (int off = 32; off; off >>= 1) s += __shfl_xor(s, off);
    vsh3[wv][t] = v / (sqrtf(s) + 1e-12f);   // wave-lockstep (verified pattern)
    float wvv = 0.f;
    if (t < O) { for (int c = 0; c < 64; ++c) wvv += W[t * 64 + c] * vsh3[wv][c]; }
    float s2 = (t < O) ? wvv * wvv : 0.f;
    for (int off = 32; off; off >>= 1) s2 += __shfl_xor(s2, off);
    const float nw = sqrtf(s2);
    if (t == 0) is_s[wv] = (nw + 1e-12f) / s2;  // 1/sigma
  }
  __syncthreads();

  const float LOG2E = 1.44269504f;
  const int px = tid & 63;
  const int rw = __builtin_amdgcn_readfirstlane(tid >> 6);  // wave row-group
  const int r0 = blockIdx.y * 16 + rw * 4;   // 4 rows r0..r0+3, single class
  const int p  = blockIdx.x * 64 + px;

  float xv[64];
  #pragma unroll
  for (int c = 0; c < 64; ++c) xv[c] = x[c * NPIX + p];

  const float* W0;
  float scl;
  if (r0 < 8)       { W0 = Wf + r0 * 64;        scl = is_s[0]; }
  else if (r0 < 16) { W0 = Wg + (r0 - 8) * 64;  scl = is_s[1]; }
  else              { W0 = Wh + (r0 - 16) * 64; scl = is_s[2]; }

  float acc[4] = {0.f, 0.f, 0.f, 0.f};
  #pragma unroll
  for (int c = 0; c < 64; ++c) {
    const float xc = xv[c];
    acc[0] += W0[c]       * xc;
    acc[1] += W0[64 + c]  * xc;
    acc[2] += W0[128 + c] * xc;
    acc[3] += W0[192 + c] * xc;
  }

  const int tile = p >> 5, nn = p & 31;
  const int kbase = tile * 512 + nn * 8;       // K row slot (ushorts)
  // V per-thread fixed part of index (depends only on nn):
  const int vfix = (nn >> 4) * 512 + ((nn >> 2) & 1) * 256
                 + (nn & 3) + 4 * ((nn >> 3) & 1);
  #pragma unroll
  for (int j = 0; j < 4; ++j) {
    const int r = r0 + j;
    if (r < 8) {
      const float val = (acc[j] * scl + bfv[r]) * LOG2E;  // exp2 fold only
      const __hip_bfloat16 h = __float2bfloat16(val);
      Qp[p * 16 + r] = *(const ushort*)&h;
    } else if (r < 16) {
      const int rk = r - 8;
      const float val = acc[j] * scl + bgv[rk];
      const __hip_bfloat16 h = __float2bfloat16(val);
      Kp[kbase + rk] = *(const ushort*)&h;
    } else {
      const int rv = r - 16;     // channel c 0..63
      const float val = acc[j] * scl + bhv[rv];
      const __hip_bfloat16 hv = __float2bfloat16(val);
      const int vidx = tile * 2048 + (rv >> 5) * 1024 + vfix + (rv & 31) * 8;
      Vt2[vidx] = *(const ushort*)&hv;
    }
  }
}

// ---------------- Kernel 2: flash attention — 32x32 MFMA, LDS-read-lean ------
// Grid (72, S), 256 threads (4 waves). Wave owns 32 m-rows (2 m-tiles).
// Per 32-n tile per wave: 1 K read + 4 V reads, 1 S-MFMA (K=16; Q upper-half
// lanes zeroed -> pad-k terms exactly 0), 4 PV MFMAs. Layout-robust: V's LDS
// order is DEFINED to mirror P's slot order, so the HW (half,slot)->k
// bijection cancels (needs only kA==kB symmetry + measured 32x32 C/D layout).
// Skeleton verified (R8/R13/R14): 4 buffers, STAGE(t+2)->vmcnt(4)->barrier.
// NOTE (R17 lesson): NO device-scope fences in the hot path — __threadfence
// per wave cost 4x (L2 writeback + cross-XCD acquire misses).
template <int S>
__global__ __launch_bounds__(256) void attn_kernel(
    const ushort* __restrict__ Qp, const ushort* __restrict__ Kp,
    const ushort* __restrict__ Vt2,
    ushort* __restrict__ Om,   // [576 mt][S][1024] bf16 (e = c*16 + m)
    float* __restrict__ Sm) {  // [576 mt][S][32]  f32 (ls at [16..31])
  constexpr int NSEG = NPIX / S;
  constexpr int NT = NSEG / 32;
  __shared__ ushort Vs[4][2048];  // 4 x 4KB
  __shared__ ushort Ks[4][512];   // 4 x 1KB (only first 512B read)
  const int tid  = threadIdx.x;
  const int w    = tid >> 6;
  const int l    = tid & 63;
  const int cc   = l & 31;
  const int h    = l >> 5;
  const int spl  = blockIdx.y;
  const int mrow = blockIdx.x * 128 + w * 32 + cc;

  bf16x8 qh = *(const bf16x8*)(Qp + mrow * 16);
  const bf16x8 zero8 = {0, 0, 0, 0, 0, 0, 0, 0};
  if (l >= 32) qh = zero8;        // kill pad-k contributions exactly
  asm volatile("" : "+v"(qh));

  const int n0 = spl * NSEG;
  const char* vsrc = (const char*)Vt2 + ((size_t)(n0 >> 5)) * 4096 + w * 1024 + l * 16;
  const char* ksrc = (const char*)Kp + ((size_t)(n0 >> 5)) * 1024 + w * 256 + l * 4;

  #define STAGE(t_) do {                                                  \
    const int b_ = (t_) & 3;                                              \
    gload_lds16(vsrc + (size_t)(t_) * 4096, (char*)&Vs[b_][0] + w * 1024);\
    gload_lds4 (ksrc + (size_t)(t_) * 1024, (char*)&Ks[b_][0] + w * 256); \
  } while (0)

  STAGE(0);
  STAGE(1);

  const unsigned ks_base = LDS_OFF(&Ks[0][0]);
  const unsigned vs_base = LDS_OFF(&Vs[0][0]);

  float ls = 0.f;
  const f32x16 zero16 = {0.f,0.f,0.f,0.f,0.f,0.f,0.f,0.f,
                         0.f,0.f,0.f,0.f,0.f,0.f,0.f,0.f};
  f32x16 accL = zero16, accH = zero16;   // c-halves 0..31 / 32..63

  for (int t = 0; t < NT; ++t) {
    const int b = t & 3;
    if (t + 2 < NT) {
      STAGE(t + 2);
      asm volatile("s_waitcnt vmcnt(4)" ::: "memory");
    } else if (t + 1 < NT) {
      asm volatile("s_waitcnt vmcnt(2)" ::: "memory");
    } else {
      asm volatile("s_waitcnt vmcnt(0)" ::: "memory");
    }
    __builtin_amdgcn_s_barrier();

    const unsigned kaddr = ks_base + b * 1024 + cc * 16;  // K row cc (bcast h)
    const unsigned vaddr = vs_base + b * 4096 + l * 16;   // linear per block
    bf16x8 kf, v00, v01, v10, v11;
    asm volatile("ds_read_b128 %0, %1"            : "=v"(kf)  : "v"(kaddr));
    asm volatile("ds_read_b128 %0, %1"            : "=v"(v00) : "v"(vaddr));
    asm volatile("ds_read_b128 %0, %1 offset:1024": "=v"(v01) : "v"(vaddr));
    asm volatile("ds_read_b128 %0, %1 offset:2048": "=v"(v10) : "v"(vaddr));
    asm volatile("ds_read_b128 %0, %1 offset:3072": "=v"(v11) : "v"(vaddr));
    asm volatile("s_waitcnt lgkmcnt(4)" ::: "memory");  // K ready (DS in-order)
    __builtin_amdgcn_sched_barrier(0);  // rule #18

    // ---- S^T[32n x 32m] = K . Q^T, single 32x32x16 MFMA (log2 domain) ----
    f32x16 s = zero16;
    s = __builtin_amdgcn_mfma_f32_32x32x16_bf16(kf, qh, s, 0, 0, 0);

    // ---- no-max softmax: P = exp2(S - 16); shift cancels in val/L ----
    float pj[16];
    #pragma unroll
    for (int r = 0; r < 16; ++r) pj[r] = exp2f(s[r] - 16.f);
    float lsum = 0.f;
    #pragma unroll
    for (int r = 0; r < 16; ++r) lsum += pj[r];
    ls += lsum;

    // ---- pack P into two A-frags (slot order == reg order) ----
    union { unsigned int u[4]; bf16x8 v; } pa0, pa1;
    #pragma unroll
    for (int jj = 0; jj < 4; ++jj) {
      unsigned int ra, rb;
      asm("v_cvt_pk_bf16_f32 %0, %1, %2" : "=v"(ra) : "v"(pj[2 * jj]), "v"(pj[2 * jj + 1]));
      asm("v_cvt_pk_bf16_f32 %0, %1, %2" : "=v"(rb) : "v"(pj[8 + 2 * jj]), "v"(pj[9 + 2 * jj]));
      pa0.u[jj] = ra;
      pa1.u[jj] = rb;
    }

    asm volatile("s_waitcnt lgkmcnt(0)" ::: "memory");  // V ready
    __builtin_amdgcn_sched_barrier(0);  // rule #18
    // ---- PV: O[32m x 64c], V frags mirror P's slot bijection ----
    accL = __builtin_amdgcn_mfma_f32_32x32x16_bf16(pa0.v, v00, accL, 0, 0, 0);
    accL = __builtin_amdgcn_mfma_f32_32x32x16_bf16(pa1.v, v01, accL, 0, 0, 0);
    accH = __builtin_amdgcn_mfma_f32_32x32x16_bf16(pa0.v, v10, accH, 0, 0, 0);
    accH = __builtin_amdgcn_mfma_f32_32x32x16_bf16(pa1.v, v11, accH, 0, 0, 0);
  }
  #undef STAGE

  // row-m sum: halves l and l+32 hold the two 16-n subsets of row m=l&31
  ls += __shfl_xor(ls, 32);

  const size_t mt0 = (size_t)blockIdx.x * 8 + w * 2;
  ushort* Ob0 = Om + (mt0 * S + spl) * 1024;
  ushort* Ob1 = Om + ((mt0 + 1) * S + spl) * 1024;
  float*  Sb0 = Sm + (mt0 * S + spl) * 32;
  float*  Sb1 = Sm + ((mt0 + 1) * S + spl) * 32;
  // D layout: reg r -> m_local = (r&3) + 8*((r>>2)&1) + 4h + 16*(r>>3)
  #pragma unroll
  for (int ch = 0; ch < 2; ++ch) {
    const f32x16 a = (ch == 0) ? accL : accH;
    #pragma unroll
    for (int r = 0; r < 16; r += 2) {
      unsigned int pk;
      asm("v_cvt_pk_bf16_f32 %0, %1, %2" : "=v"(pk) : "v"(a[r]), "v"(a[r + 1]));
      const int m16 = (r & 3) + 8 * ((r >> 2) & 1) + 4 * h;  // even ✓
      ushort* Ob = (r < 8) ? Ob0 : Ob1;
      *(unsigned int*)(Ob + (ch * 32 + cc) * 16 + m16) = pk;
    }
  }
  if (l < 32) {
    float* SbX = (l < 16) ? Sb0 : Sb1;
    SbX[16 + (l & 15)] = ls;
  }
}

// ---------------- Kernel 3: combine split partials (pure sum) ----------------
// Grid 2304: each block handles a quarter (256 elems) of one m-tile.
template <int S>
__global__ __launch_bounds__(256) void combine_kernel(
    const ushort* __restrict__ Om, const float* __restrict__ Sm,
    const float* __restrict__ x, const float* __restrict__ gammap,
    float* __restrict__ out) {
  const int mt = blockIdx.x >> 2;
  const int m0 = mt * 16;
  const int e  = (blockIdx.x & 3) * 256 + threadIdx.x;
  const float gamma = gammap[0];
  const float* Sb = Sm + (size_t)mt * S * 32;
  const ushort* Ob = Om + (size_t)mt * S * 1024;
  const int m = e & 15, c = e >> 4;
  float L = 0.f, val = 0.f;
  #pragma unroll
  for (int s = 0; s < S; ++s) {
    L += Sb[s * 32 + 16 + m];
    union { unsigned int i; float f; } cv;
    cv.i = ((unsigned int)Ob[s * 1024 + e]) << 16;
    val += cv.f;
  }
  const int idx = c * NPIX + m0 + m;
  out[idx] = gamma * (val / L) + x[idx];
}

// ---------------- launcher ---------------------------------------------------
extern "C" void kernel_launch(void* const* d_in, const int* in_sizes, int n_in,
                              void* d_out, int out_size, void* d_ws, size_t ws_size,
                              hipStream_t stream) {
  const float* x     = (const float*)d_in[0];
  const float* Wf    = (const float*)d_in[1];
  const float* bf    = (const float*)d_in[2];
  const float* Wg    = (const float*)d_in[3];
  const float* bg    = (const float*)d_in[4];
  const float* Wh    = (const float*)d_in[5];
  const float* bh    = (const float*)d_in[6];
  const float* gamma = (const float*)d_in[7];
  const float* uf    = (const float*)d_in[8];
  const float* ug    = (const float*)d_in[9];
  const float* uh    = (const float*)d_in[10];
  float* out = (float*)d_out;

  char* ws = (char*)d_ws;
  ushort* Qp  = (ushort*)(ws + 256);                                 // 294912 B
  ushort* Kp  = (ushort*)(ws + 256 + NPIX * 16 * 2);                 // 294912 B
  ushort* Vt2 = (ushort*)(ws + 256 + 2 * NPIX * 16 * 2);             // 1179648 B
  const size_t off = 256 + (size_t)2 * NPIX * 16 * 2 + (size_t)NPIX * 64 * 2;
  ushort* Om = (ushort*)(ws + off);
  const size_t need16 = off + (size_t)MTILES * 16 * 1024 * 2 + (size_t)MTILES * 16 * 32 * 4;

  fgh_kernel<<<dim3(NPIX / 64, 5), 256, 0, stream>>>(x, Wf, bf, Wg, bg, Wh, bh,
                                                     uf, ug, uh, Qp, Kp, Vt2);
  if (ws_size >= need16) {
    float* Sm = (float*)(ws + off + (size_t)MTILES * 16 * 1024 * 2);
    attn_kernel<16><<<dim3(NPIX / 128, 16), 256, 0, stream>>>(Qp, Kp, Vt2, Om, Sm);
    combine_kernel<16><<<MTILES * 4, 256, 0, stream>>>(Om, Sm, x, gamma, out);
  } else {
    float* Sm = (float*)(ws + off + (size_t)MTILES * 8 * 1024 * 2);
    attn_kernel<8><<<dim3(NPIX / 128, 8), 256, 0, stream>>>(Qp, Kp, Vt2, Om, Sm);
    combine_kernel<8><<<MTILES * 4, 256, 0, stream>>>(Om, Sm, x, gamma, out);
  }
}